// Round 19
// baseline (617.642 us; speedup 1.0000x reference)
//
#include <hip/hip_runtime.h>

#define K_TPLT 16
#define M_NODES 10
#define M2 5              // float2 pairs per problem
#define DFEAT 128
#define NMAXW 4           // node-blocks per wave (2 waves x 4 x 64 = 512 >= 448)
#define NPROB 2           // problems (k0, k0+8) per block
#define N_ITER 50
#define NEG_BIG -1e30f
#define LOG2E 1.44269504088896340736f
#define LN2   0.69314718055994530942f

#define EXP2F(x) __builtin_amdgcn_exp2f(x)
#define LOG2F(x) __builtin_amdgcn_logf(x)   // v_log_f32 = log base 2

typedef float v2f __attribute__((ext_vector_type(2)));

__global__ void zero_counts_k(int* counts, int G) {
    int g = blockIdx.x * blockDim.x + threadIdx.x;
    if (g < G) counts[g] = 0;
}

__global__ void count_nodes_k(const int* __restrict__ batch, int* counts, int N) {
    int i = blockIdx.x * blockDim.x + threadIdx.x;
    if (i < N) atomicAdd(&counts[batch[i]], 1);
}

__global__ void scan_counts_k(const int* __restrict__ counts, int* starts, int G) {
    __shared__ int sc[1024];
    int t = threadIdx.x;
    for (int g = t; g < G; g += blockDim.x) sc[g] = counts[g];
    __syncthreads();
    for (int g = t; g < G; g += blockDim.x) {
        int s = 0;
        for (int j = 0; j < g; ++j) s += sc[j];
        starts[g] = s;
    }
}

template <int CTRL>
__device__ __forceinline__ float dpp_add(float v) {
    return v + __int_as_float(__builtin_amdgcn_update_dpp(
        0, __float_as_int(v), CTRL, 0xF, 0xF, true));
}
// Full 64-lane sum, pure VALU DPP; total broadcast via readlane(63).
__device__ __forceinline__ float wred_add_u(float v) {
    v = dpp_add<0xB1>(v);
    v = dpp_add<0x4E>(v);
    v = dpp_add<0x141>(v);
    v = dpp_add<0x140>(v);
    v = dpp_add<0x142>(v);   // row_bcast15
    v = dpp_add<0x143>(v);   // row_bcast31 -> lane63 = total
    return __int_as_float(__builtin_amdgcn_readlane(__float_as_int(v), 63));
}
template <int CTRL>
__device__ __forceinline__ float dpp_max(float v) {
    return fmaxf(v, __int_as_float(__builtin_amdgcn_update_dpp(
        0, __float_as_int(v), CTRL, 0xF, 0xF, true)));
}
__device__ __forceinline__ float wred_max(float v) {
    v = dpp_max<0xB1>(v);
    v = dpp_max<0x4E>(v);
    v = dpp_max<0x141>(v);
    v = dpp_max<0x140>(v);
    v = fmaxf(v, __shfl_xor(v, 16));
    v = fmaxf(v, __shfl_xor(v, 32));
    return v;
}
__device__ __forceinline__ v2f v2max(v2f a, v2f b) { return __builtin_elementwise_max(a, b); }
__device__ __forceinline__ float dot4(const float4& a, const float4& b) {
    return a.x * b.x + a.y * b.y + a.z * b.z + a.w * b.w;
}

// 128-thread block = 2 waves; block handles problems (g,k0) and (g,k0+8).
// Wave w owns node-blocks {w, w+2, w+4, w+6} (interleaved for load balance).
// Per-iteration partial column sums combined through parity-double-buffered
// LDS with ONE barrier (R9-verified sync: skew <= 1 iter => alternating slot
// kills the WAR hazard). x float4 loads shared across the two k's (R17),
// packed v2f math + all-DPP reductions (R18). Per-problem math is the
// verified scheme: log-domain L (row max 0), fresh per-node row shift per
// iteration, exact g-update with +g2, iteration-1 exact via per-column csh.
__global__ __launch_bounds__(128) void sinkhorn_tw_k(
    const float* __restrict__ x, const float* __restrict__ tplt,
    const float* __restrict__ q0, const int* __restrict__ starts,
    const int* __restrict__ counts, float* __restrict__ out, int G)
{
    const int bid  = blockIdx.x;
    const int g    = bid % G;      // same-g blocks land on same XCD (G % 8 == 0)
    const int k0   = bid / G;      // k0 in [0,8)
    const int w    = threadIdx.x >> 6;
    const int lane = threadIdx.x & 63;

    __shared__ float sm_max[NPROB][2][M_NODES];
    __shared__ float sm_acc[2][NPROB][2][M_NODES];   // [parity][p][wave][m]
    __shared__ float sm_out[NPROB][2];

    const int start = starts[g];
    const int count = counts[g];
    const float a   = 1.0f / (float)count;
    const float la2 = -LOG2F((float)count);            // log2(a)

    // lbla[p][m] = log2_softmax(q0[k,:]) - la2  (v2f pairs, both waves)
    v2f lblav[NPROB][M2];
#pragma unroll
    for (int p = 0; p < NPROB; ++p) {
        const float* qk = q0 + (k0 + 8 * p) * M_NODES;
        float qv[M_NODES];
        float qmax = NEG_BIG;
#pragma unroll
        for (int m = 0; m < M_NODES; ++m) { qv[m] = qk[m]; qmax = fmaxf(qmax, qv[m]); }
        float qs = 0.f;
#pragma unroll
        for (int m = 0; m < M_NODES; ++m) {
            qv[m] = (qv[m] - qmax) * LOG2E;
            qs += EXP2F(qv[m]);
        }
        const float corr = LOG2F(qs);
#pragma unroll
        for (int mm = 0; mm < M2; ++mm)
            lblav[p][mm] = (v2f){qv[2 * mm] - corr - la2, qv[2 * mm + 1] - corr - la2};
    }

    bool act[NMAXW];
#pragma unroll
    for (int j = 0; j < NMAXW; ++j) act[j] = (lane + 64 * (2 * j + w)) < count;

    // Lv[p][j][mm] = (negC*log2e) - nsh_row, v2f pairs (log domain, <= 0)
    v2f Lv[NPROB][NMAXW][M2];
    float nsum[NPROB];             // per-lane partial sum of nsh over this wave's rows
    v2f cshv[NPROB][M2];
    {
        const float* Tk0 = tplt + (size_t)k0 * M_NODES * DFEAT;
        const float* Tk1 = tplt + (size_t)(k0 + 8) * M_NODES * DFEAT;
        float x2[NMAXW];
        v2f t2v[NPROB][M2];
#pragma unroll
        for (int j = 0; j < NMAXW; ++j) {
            x2[j] = 0.f;
#pragma unroll
            for (int p = 0; p < NPROB; ++p)
#pragma unroll
                for (int mm = 0; mm < M2; ++mm) Lv[p][j][mm] = (v2f){0.f, 0.f};
        }
#pragma unroll
        for (int p = 0; p < NPROB; ++p)
#pragma unroll
            for (int mm = 0; mm < M2; ++mm) t2v[p][mm] = (v2f){0.f, 0.f};

        for (int jf = 0; jf < DFEAT; jf += 4) {
            float4 xv[NMAXW];
#pragma unroll
            for (int j = 0; j < NMAXW; ++j) {
                if (act[j]) {
                    xv[j] = *(const float4*)(x + (size_t)(start + lane + 64 * (2 * j + w)) * DFEAT + jf);
                } else {
                    xv[j].x = xv[j].y = xv[j].z = xv[j].w = 0.f;
                }
                x2[j] += dot4(xv[j], xv[j]);
            }
#pragma unroll
            for (int mm = 0; mm < M2; ++mm) {
                const float4 ta0 = *(const float4*)(Tk0 + (2 * mm)     * DFEAT + jf);
                const float4 tb0 = *(const float4*)(Tk0 + (2 * mm + 1) * DFEAT + jf);
                const float4 ta1 = *(const float4*)(Tk1 + (2 * mm)     * DFEAT + jf);
                const float4 tb1 = *(const float4*)(Tk1 + (2 * mm + 1) * DFEAT + jf);
                t2v[0][mm] += (v2f){dot4(ta0, ta0), dot4(tb0, tb0)};
                t2v[1][mm] += (v2f){dot4(ta1, ta1), dot4(tb1, tb1)};
#pragma unroll
                for (int j = 0; j < NMAXW; ++j) {
                    Lv[0][j][mm] += (v2f){dot4(xv[j], ta0), dot4(xv[j], tb0)};
                    Lv[1][j][mm] += (v2f){dot4(xv[j], ta1), dot4(xv[j], tb1)};
                }
            }
        }
#pragma unroll
        for (int p = 0; p < NPROB; ++p) {
            nsum[p] = 0.f;
#pragma unroll
            for (int j = 0; j < NMAXW; ++j) {
                const v2f x2v = {x2[j], x2[j]};
                v2f mxv = (v2f){NEG_BIG, NEG_BIG};
#pragma unroll
                for (int mm = 0; mm < M2; ++mm) {
                    Lv[p][j][mm] = (Lv[p][j][mm] * 2.f - x2v - t2v[p][mm]) * LOG2E; // negC2
                    mxv = v2max(mxv, Lv[p][j][mm]);
                }
                const float mx = fmaxf(mxv.x, mxv.y);
                if (act[j]) nsum[p] += mx;
                const v2f mxb = {mx, mx};
#pragma unroll
                for (int mm = 0; mm < M2; ++mm) Lv[p][j][mm] -= mxb;   // <= 0
            }
            // per-column max: wave partial -> LDS -> cross-wave combine
#pragma unroll
            for (int m = 0; m < M_NODES; ++m) {
                float c = NEG_BIG;
#pragma unroll
                for (int j = 0; j < NMAXW; ++j) {
                    const float lv = (m & 1) ? Lv[p][j][m >> 1].y : Lv[p][j][m >> 1].x;
                    c = act[j] ? fmaxf(c, lv) : c;
                }
                c = wred_max(c);
                if (lane == 0) sm_max[p][w][m] = c;
            }
        }
    }
    __syncthreads();
#pragma unroll
    for (int p = 0; p < NPROB; ++p)
#pragma unroll
        for (int mm = 0; mm < M2; ++mm)
            cshv[p][mm] = (v2f){fmaxf(sm_max[p][0][2 * mm],     sm_max[p][1][2 * mm]),
                                fmaxf(sm_max[p][0][2 * mm + 1], sm_max[p][1][2 * mm + 1])};

    v2f g2v[NPROB][M2];

    // ---- iteration 0 (parity 0): g = 0, exact with per-column shift csh ----
    {
        v2f acc[NPROB][M2];
#pragma unroll
        for (int p = 0; p < NPROB; ++p) {
            v2f w0v[M2];
#pragma unroll
            for (int mm = 0; mm < M2; ++mm) {
                w0v[mm] = (v2f){EXP2F(cshv[p][mm].x), EXP2F(cshv[p][mm].y)};
                acc[p][mm] = (v2f){0.f, 0.f};
            }
#pragma unroll
            for (int j = 0; j < NMAXW; ++j) {
                if (act[j]) {
                    v2f Ev[M2];
                    v2f Dp = (v2f){0.f, 0.f};
#pragma unroll
                    for (int mm = 0; mm < M2; ++mm) {
                        Ev[mm] = (v2f){EXP2F(Lv[p][j][mm].x - cshv[p][mm].x),
                                       EXP2F(Lv[p][j][mm].y - cshv[p][mm].y)};
                        Dp += Ev[mm] * w0v[mm];
                    }
                    const float D = Dp.x + Dp.y;             // >= 1
                    const float r = __builtin_amdgcn_rcpf(D);
                    const v2f rv = {r, r};
#pragma unroll
                    for (int mm = 0; mm < M2; ++mm) acc[p][mm] += Ev[mm] * rv;
                }
            }
#pragma unroll
            for (int m = 0; m < M_NODES; ++m) {
                const float s = wred_add_u((m & 1) ? acc[p][m >> 1].y : acc[p][m >> 1].x);
                if (lane == 0) sm_acc[0][p][w][m] = s;
            }
        }
        __syncthreads();
#pragma unroll
        for (int p = 0; p < NPROB; ++p)
#pragma unroll
            for (int mm = 0; mm < M2; ++mm) {
                const float s0 = sm_acc[0][p][0][2 * mm]     + sm_acc[0][p][1][2 * mm];
                const float s1 = sm_acc[0][p][0][2 * mm + 1] + sm_acc[0][p][1][2 * mm + 1];
                g2v[p][mm].x = lblav[p][mm].x - cshv[p][mm].x - LOG2F(fmaxf(s0, 1e-35f));
                g2v[p][mm].y = lblav[p][mm].y - cshv[p][mm].y - LOG2F(fmaxf(s1, 1e-35f));
            }
    }

    // ---- iterations 1..N_ITER-1: fresh per-node row shift; parity slots ----
    for (int it = 1; it < N_ITER; ++it) {
        const int par = it & 1;
        v2f acc[NPROB][M2];
#pragma unroll
        for (int p = 0; p < NPROB; ++p)
#pragma unroll
            for (int mm = 0; mm < M2; ++mm) acc[p][mm] = (v2f){0.f, 0.f};

#pragma unroll
        for (int j = 0; j < NMAXW; ++j) {
            if (act[j]) {
#pragma unroll
                for (int p = 0; p < NPROB; ++p) {
                    v2f z[M2];
#pragma unroll
                    for (int mm = 0; mm < M2; ++mm) z[mm] = g2v[p][mm] + Lv[p][j][mm];
                    v2f mzv = v2max(z[0], z[1]);
                    mzv = v2max(mzv, z[2]);
                    mzv = v2max(mzv, z[3]);
                    mzv = v2max(mzv, z[4]);
                    const float zmax = fmaxf(mzv.x, mzv.y);
                    const v2f zb = {zmax, zmax};
                    v2f e[M2];
                    v2f Dp = (v2f){0.f, 0.f};
#pragma unroll
                    for (int mm = 0; mm < M2; ++mm) {
                        const v2f d = z[mm] - zb;
                        e[mm] = (v2f){EXP2F(d.x), EXP2F(d.y)};
                        Dp += e[mm];
                    }
                    const float D = Dp.x + Dp.y;         // in [1,10]
                    const float r = __builtin_amdgcn_rcpf(D);
                    const v2f rv = {r, r};
#pragma unroll
                    for (int mm = 0; mm < M2; ++mm) acc[p][mm] += e[mm] * rv;
                }
            }
        }
#pragma unroll
        for (int p = 0; p < NPROB; ++p)
#pragma unroll
            for (int m = 0; m < M_NODES; ++m) {
                const float s = wred_add_u((m & 1) ? acc[p][m >> 1].y : acc[p][m >> 1].x);
                if (lane == 0) sm_acc[par][p][w][m] = s;
            }
        __syncthreads();
#pragma unroll
        for (int p = 0; p < NPROB; ++p)
#pragma unroll
            for (int mm = 0; mm < M2; ++mm) {
                const float s0 = sm_acc[par][p][0][2 * mm]     + sm_acc[par][p][1][2 * mm];
                const float s1 = sm_acc[par][p][0][2 * mm + 1] + sm_acc[par][p][1][2 * mm + 1];
                g2v[p][mm].x = lblav[p][mm].x + g2v[p][mm].x - LOG2F(fmaxf(s0, 1e-35f));
                g2v[p][mm].y = lblav[p][mm].y + g2v[p][mm].y - LOG2F(fmaxf(s1, 1e-35f));
            }
    }

    // ---- epilogue: final f fused with transport cost ----
#pragma unroll
    for (int p = 0; p < NPROB; ++p) {
        float accum = nsum[p];
#pragma unroll
        for (int j = 0; j < NMAXW; ++j) {
            if (act[j]) {
                v2f z[M2];
#pragma unroll
                for (int mm = 0; mm < M2; ++mm) z[mm] = g2v[p][mm] + Lv[p][j][mm];
                v2f mzv = v2max(z[0], z[1]);
                mzv = v2max(mzv, z[2]);
                mzv = v2max(mzv, z[3]);
                mzv = v2max(mzv, z[4]);
                const float zmax = fmaxf(mzv.x, mzv.y);
                const v2f zb = {zmax, zmax};
                v2f Dp = (v2f){0.f, 0.f};
                v2f qv = (v2f){0.f, 0.f};
#pragma unroll
                for (int mm = 0; mm < M2; ++mm) {
                    const v2f d = z[mm] - zb;
                    const v2f e = {EXP2F(d.x), EXP2F(d.y)};
                    Dp += e;
                    qv += e * Lv[p][j][mm];
                }
                const float D = Dp.x + Dp.y;
                const float r = __builtin_amdgcn_rcpf(D);
                accum += (qv.x + qv.y) * r;
            }
        }
        accum = wred_add_u(accum);
        if (lane == 0) sm_out[p][w] = accum;
    }
    __syncthreads();
    if (w == 0 && lane == 0) {
#pragma unroll
        for (int p = 0; p < NPROB; ++p)
            out[(size_t)g * K_TPLT + (k0 + 8 * p)] =
                -a * LN2 * (sm_out[p][0] + sm_out[p][1]);
    }
}

extern "C" void kernel_launch(void* const* d_in, const int* in_sizes, int n_in,
                              void* d_out, int out_size, void* d_ws, size_t ws_size,
                              hipStream_t stream) {
    const float* x    = (const float*)d_in[0];
    const float* tplt = (const float*)d_in[1];
    const float* q0   = (const float*)d_in[2];
    const int* batch  = (const int*)d_in[3];
    const int N = in_sizes[3];
    const int G = out_size / K_TPLT;

    int* counts = (int*)d_ws;
    int* starts = counts + G;

    zero_counts_k<<<(G + 255) / 256, 256, 0, stream>>>(counts, G);
    count_nodes_k<<<(N + 255) / 256, 256, 0, stream>>>(batch, counts, N);
    scan_counts_k<<<1, 256, 0, stream>>>(counts, starts, G);
    sinkhorn_tw_k<<<G * (K_TPLT / 2), 128, 0, stream>>>(x, tplt, q0, starts, counts,
                                                        (float*)d_out, G);
}

// Round 20
// 483.052 us; speedup vs baseline: 1.2786x; 1.2786x over previous
//
#include <hip/hip_runtime.h>

#define K_TPLT 16
#define M_NODES 10
#define M2 5              // float2 pairs
#define DFEAT 128
#define NMAX 7            // supports up to 448 nodes per graph (actual: 400)
#define N_ITER 50
#define NEG_BIG -1e30f
#define LOG2E 1.44269504088896340736f
#define LN2   0.69314718055994530942f

#define EXP2F(x) __builtin_amdgcn_exp2f(x)
#define LOG2F(x) __builtin_amdgcn_logf(x)   // v_log_f32 = log base 2

typedef float v2f __attribute__((ext_vector_type(2)));

__global__ void zero_counts_k(int* counts, int G) {
    int g = blockIdx.x * blockDim.x + threadIdx.x;
    if (g < G) counts[g] = 0;
}

__global__ void count_nodes_k(const int* __restrict__ batch, int* counts, int N) {
    int i = blockIdx.x * blockDim.x + threadIdx.x;
    if (i < N) atomicAdd(&counts[batch[i]], 1);
}

__global__ void scan_counts_k(const int* __restrict__ counts, int* starts, int G) {
    __shared__ int sc[1024];
    int t = threadIdx.x;
    for (int g = t; g < G; g += blockDim.x) sc[g] = counts[g];
    __syncthreads();
    for (int g = t; g < G; g += blockDim.x) {
        int s = 0;
        for (int j = 0; j < g; ++j) s += sc[j];
        starts[g] = s;
    }
}

template <int CTRL>
__device__ __forceinline__ float dpp_add(float v) {
    return v + __int_as_float(__builtin_amdgcn_update_dpp(
        0, __float_as_int(v), CTRL, 0xF, 0xF, true));
}
// Full 64-lane sum, pure VALU DPP; total broadcast via readlane(63).
__device__ __forceinline__ float wred_add_u(float v) {
    v = dpp_add<0xB1>(v);
    v = dpp_add<0x4E>(v);
    v = dpp_add<0x141>(v);
    v = dpp_add<0x140>(v);
    v = dpp_add<0x142>(v);   // row_bcast15
    v = dpp_add<0x143>(v);   // row_bcast31 -> lane63 = total
    return __int_as_float(__builtin_amdgcn_readlane(__float_as_int(v), 63));
}
template <int CTRL>
__device__ __forceinline__ float dpp_max(float v) {
    return fmaxf(v, __int_as_float(__builtin_amdgcn_update_dpp(
        0, __float_as_int(v), CTRL, 0xF, 0xF, true)));
}
__device__ __forceinline__ float wred_max(float v) {
    v = dpp_max<0xB1>(v);
    v = dpp_max<0x4E>(v);
    v = dpp_max<0x141>(v);
    v = dpp_max<0x140>(v);
    v = fmaxf(v, __shfl_xor(v, 16));
    v = fmaxf(v, __shfl_xor(v, 32));
    return v;
}
__device__ __forceinline__ v2f v2max(v2f a, v2f b) { return __builtin_elementwise_max(a, b); }
__device__ __forceinline__ float dot4(const float4& a, const float4& b) {
    return a.x * b.x + a.y * b.y + a.z * b.z + a.w * b.w;
}

// ONE wave per (graph, template) problem -- 4096 independent waves
// (4/SIMD supplied; best-measured occupancy scaling), no barriers, no LDS.
// Math identical to the R15/R17/R18-verified scheme: log-domain L (row max
// 0), fresh per-node row shift every iteration, exact g-update with +g2,
// iteration-1 exact via per-column shift csh. Codegen: packed v2f state
// (v_pk_*_f32) + all-DPP reductions (R18's -5%), with NPROB stripped to 1
// to halve per-wave serial work and double supplied waves vs R18.
__global__ __launch_bounds__(64) void sinkhorn_tw_k(
    const float* __restrict__ x, const float* __restrict__ tplt,
    const float* __restrict__ q0, const int* __restrict__ starts,
    const int* __restrict__ counts, float* __restrict__ out, int G)
{
    const int bid  = blockIdx.x;
    const int g    = bid % G;      // same-g blocks land on same XCD (G % 8 == 0)
    const int k    = bid / G;
    const int lane = threadIdx.x;

    const int start = starts[g];
    const int count = counts[g];
    const float a   = 1.0f / (float)count;
    const float la2 = -LOG2F((float)count);            // log2(a)

    // lbla[m] = log2_softmax(q0[k,:]) - la2  (v2f pairs)
    v2f lblav[M2];
    {
        const float* qk = q0 + k * M_NODES;
        float qv[M_NODES];
        float qmax = NEG_BIG;
#pragma unroll
        for (int m = 0; m < M_NODES; ++m) { qv[m] = qk[m]; qmax = fmaxf(qmax, qv[m]); }
        float qs = 0.f;
#pragma unroll
        for (int m = 0; m < M_NODES; ++m) {
            qv[m] = (qv[m] - qmax) * LOG2E;
            qs += EXP2F(qv[m]);
        }
        const float corr = LOG2F(qs);
#pragma unroll
        for (int mm = 0; mm < M2; ++mm)
            lblav[mm] = (v2f){qv[2 * mm] - corr - la2, qv[2 * mm + 1] - corr - la2};
    }

    bool act[NMAX];
#pragma unroll
    for (int i = 0; i < NMAX; ++i) act[i] = (lane + i * 64) < count;

    // Lv[i][mm] = (negC*log2e) - nsh_i, v2f pairs (log domain, <= 0)
    v2f Lv[NMAX][M2];
    float nsum;                    // per-lane sum of nsh_i over active i
    v2f cshv[M2];
    {
        const float* Tk = tplt + (size_t)k * M_NODES * DFEAT;
        float x2[NMAX];
        v2f t2v[M2];
#pragma unroll
        for (int i = 0; i < NMAX; ++i) {
            x2[i] = 0.f;
#pragma unroll
            for (int mm = 0; mm < M2; ++mm) Lv[i][mm] = (v2f){0.f, 0.f};
        }
#pragma unroll
        for (int mm = 0; mm < M2; ++mm) t2v[mm] = (v2f){0.f, 0.f};

        for (int jf = 0; jf < DFEAT; jf += 4) {
            float4 xv[NMAX];
#pragma unroll
            for (int i = 0; i < NMAX; ++i) {
                if (act[i]) {
                    xv[i] = *(const float4*)(x + (size_t)(start + lane + i * 64) * DFEAT + jf);
                } else {
                    xv[i].x = xv[i].y = xv[i].z = xv[i].w = 0.f;
                }
                x2[i] += dot4(xv[i], xv[i]);
            }
#pragma unroll
            for (int mm = 0; mm < M2; ++mm) {
                const float4 ta = *(const float4*)(Tk + (2 * mm)     * DFEAT + jf);
                const float4 tb = *(const float4*)(Tk + (2 * mm + 1) * DFEAT + jf);
                t2v[mm] += (v2f){dot4(ta, ta), dot4(tb, tb)};
#pragma unroll
                for (int i = 0; i < NMAX; ++i)
                    Lv[i][mm] += (v2f){dot4(xv[i], ta), dot4(xv[i], tb)};
            }
        }
        nsum = 0.f;
#pragma unroll
        for (int i = 0; i < NMAX; ++i) {
            const v2f x2v = {x2[i], x2[i]};
            v2f mxv = (v2f){NEG_BIG, NEG_BIG};
#pragma unroll
            for (int mm = 0; mm < M2; ++mm) {
                Lv[i][mm] = (Lv[i][mm] * 2.f - x2v - t2v[mm]) * LOG2E;  // negC2
                mxv = v2max(mxv, Lv[i][mm]);
            }
            const float mx = fmaxf(mxv.x, mxv.y);
            if (act[i]) nsum += mx;
            const v2f mxb = {mx, mx};
#pragma unroll
            for (int mm = 0; mm < M2; ++mm) Lv[i][mm] -= mxb;           // <= 0
        }
        // per-column max over active entries
        float csh[M_NODES];
#pragma unroll
        for (int m = 0; m < M_NODES; ++m) {
            float c = NEG_BIG;
#pragma unroll
            for (int i = 0; i < NMAX; ++i) {
                const float lv = (m & 1) ? Lv[i][m >> 1].y : Lv[i][m >> 1].x;
                c = act[i] ? fmaxf(c, lv) : c;
            }
            csh[m] = wred_max(c);
        }
#pragma unroll
        for (int mm = 0; mm < M2; ++mm) cshv[mm] = (v2f){csh[2 * mm], csh[2 * mm + 1]};
    }

    v2f g2v[M2];

    // ---- iteration 1: g = 0, exact with per-column shift csh ----
    {
        v2f w0v[M2], acc[M2];
#pragma unroll
        for (int mm = 0; mm < M2; ++mm) {
            w0v[mm] = (v2f){EXP2F(cshv[mm].x), EXP2F(cshv[mm].y)};
            acc[mm] = (v2f){0.f, 0.f};
        }
#pragma unroll
        for (int i = 0; i < NMAX; ++i) {
            if (act[i]) {
                v2f Ev[M2];
                v2f Dp = (v2f){0.f, 0.f};
#pragma unroll
                for (int mm = 0; mm < M2; ++mm) {
                    Ev[mm] = (v2f){EXP2F(Lv[i][mm].x - cshv[mm].x),
                                   EXP2F(Lv[i][mm].y - cshv[mm].y)};
                    Dp += Ev[mm] * w0v[mm];              // = sum 2^L per pair
                }
                const float D = Dp.x + Dp.y;             // >= 1
                const float r = __builtin_amdgcn_rcpf(D);
                const v2f rv = {r, r};
#pragma unroll
                for (int mm = 0; mm < M2; ++mm) acc[mm] += Ev[mm] * rv;
            }
        }
#pragma unroll
        for (int mm = 0; mm < M2; ++mm) {
            const float s0 = wred_add_u(acc[mm].x);
            const float s1 = wred_add_u(acc[mm].y);
            g2v[mm].x = lblav[mm].x - cshv[mm].x - LOG2F(fmaxf(s0, 1e-35f));
            g2v[mm].y = lblav[mm].y - cshv[mm].y - LOG2F(fmaxf(s1, 1e-35f));
        }
    }

    // ---- iterations 2..N_ITER: fresh per-node row shift each time ----
    for (int it = 1; it < N_ITER; ++it) {
        v2f acc[M2];
#pragma unroll
        for (int mm = 0; mm < M2; ++mm) acc[mm] = (v2f){0.f, 0.f};

#pragma unroll
        for (int i = 0; i < NMAX; ++i) {
            if (act[i]) {
                v2f z[M2];
#pragma unroll
                for (int mm = 0; mm < M2; ++mm) z[mm] = g2v[mm] + Lv[i][mm];
                v2f mzv = v2max(z[0], z[1]);
                mzv = v2max(mzv, z[2]);
                mzv = v2max(mzv, z[3]);
                mzv = v2max(mzv, z[4]);
                const float zmax = fmaxf(mzv.x, mzv.y);
                const v2f zb = {zmax, zmax};
                v2f e[M2];
                v2f Dp = (v2f){0.f, 0.f};
#pragma unroll
                for (int mm = 0; mm < M2; ++mm) {
                    const v2f d = z[mm] - zb;
                    e[mm] = (v2f){EXP2F(d.x), EXP2F(d.y)};
                    Dp += e[mm];
                }
                const float D = Dp.x + Dp.y;             // in [1,10]
                const float r = __builtin_amdgcn_rcpf(D);
                const v2f rv = {r, r};
#pragma unroll
                for (int mm = 0; mm < M2; ++mm) acc[mm] += e[mm] * rv;
            }
        }
#pragma unroll
        for (int mm = 0; mm < M2; ++mm) {
            const float s0 = wred_add_u(acc[mm].x);
            const float s1 = wred_add_u(acc[mm].y);
            g2v[mm].x = lblav[mm].x + g2v[mm].x - LOG2F(fmaxf(s0, 1e-35f));
            g2v[mm].y = lblav[mm].y + g2v[mm].y - LOG2F(fmaxf(s1, 1e-35f));
        }
    }

    // ---- epilogue: final f fused with transport cost ----
    // per_node = -a*ln2*( nsh_i + r * sum_m e_m L_m ); nsh pre-summed in nsum
    float accum = nsum;
#pragma unroll
    for (int i = 0; i < NMAX; ++i) {
        if (act[i]) {
            v2f z[M2];
#pragma unroll
            for (int mm = 0; mm < M2; ++mm) z[mm] = g2v[mm] + Lv[i][mm];
            v2f mzv = v2max(z[0], z[1]);
            mzv = v2max(mzv, z[2]);
            mzv = v2max(mzv, z[3]);
            mzv = v2max(mzv, z[4]);
            const float zmax = fmaxf(mzv.x, mzv.y);
            const v2f zb = {zmax, zmax};
            v2f Dp = (v2f){0.f, 0.f};
            v2f qv = (v2f){0.f, 0.f};
#pragma unroll
            for (int mm = 0; mm < M2; ++mm) {
                const v2f d = z[mm] - zb;
                const v2f e = {EXP2F(d.x), EXP2F(d.y)};
                Dp += e;
                qv += e * Lv[i][mm];
            }
            const float D = Dp.x + Dp.y;
            const float r = __builtin_amdgcn_rcpf(D);
            accum += (qv.x + qv.y) * r;
        }
    }
    accum = wred_add_u(accum);
    if (lane == 0) out[(size_t)g * K_TPLT + k] = -a * LN2 * accum;
}

extern "C" void kernel_launch(void* const* d_in, const int* in_sizes, int n_in,
                              void* d_out, int out_size, void* d_ws, size_t ws_size,
                              hipStream_t stream) {
    const float* x    = (const float*)d_in[0];
    const float* tplt = (const float*)d_in[1];
    const float* q0   = (const float*)d_in[2];
    const int* batch  = (const int*)d_in[3];
    const int N = in_sizes[3];
    const int G = out_size / K_TPLT;

    int* counts = (int*)d_ws;
    int* starts = counts + G;

    zero_counts_k<<<(G + 255) / 256, 256, 0, stream>>>(counts, G);
    count_nodes_k<<<(N + 255) / 256, 256, 0, stream>>>(batch, counts, N);
    scan_counts_k<<<1, 256, 0, stream>>>(counts, starts, G);
    sinkhorn_tw_k<<<G * K_TPLT, 64, 0, stream>>>(x, tplt, q0, starts, counts,
                                                 (float*)d_out, G);
}

// Round 21
// 463.344 us; speedup vs baseline: 1.3330x; 1.0425x over previous
//
#include <hip/hip_runtime.h>

#define K_TPLT 16
#define M_NODES 10
#define M2 5              // float2 pairs per problem
#define DFEAT 128
#define NMAX 7            // supports up to 448 nodes per graph (actual: 400)
#define NPROB 2           // problems (k, k+8) per wave
#define N_ITER 50
#define NEG_BIG -1e30f
#define LOG2E 1.44269504088896340736f
#define LN2   0.69314718055994530942f

#define EXP2F(x) __builtin_amdgcn_exp2f(x)
#define LOG2F(x) __builtin_amdgcn_logf(x)   // v_log_f32 = log base 2

typedef float v2f __attribute__((ext_vector_type(2)));

__global__ void zero_counts_k(int* counts, int G) {
    int g = blockIdx.x * blockDim.x + threadIdx.x;
    if (g < G) counts[g] = 0;
}

__global__ void count_nodes_k(const int* __restrict__ batch, int* counts, int N) {
    int i = blockIdx.x * blockDim.x + threadIdx.x;
    if (i < N) atomicAdd(&counts[batch[i]], 1);
}

__global__ void scan_counts_k(const int* __restrict__ counts, int* starts, int G) {
    __shared__ int sc[1024];
    int t = threadIdx.x;
    for (int g = t; g < G; g += blockDim.x) sc[g] = counts[g];
    __syncthreads();
    for (int g = t; g < G; g += blockDim.x) {
        int s = 0;
        for (int j = 0; j < g; ++j) s += sc[j];
        starts[g] = s;
    }
}

template <int CTRL>
__device__ __forceinline__ float dpp_add(float v) {
    return v + __int_as_float(__builtin_amdgcn_update_dpp(
        0, __float_as_int(v), CTRL, 0xF, 0xF, true));
}
// Full wave sum, pure VALU DPP; total broadcast via readlane(63).
__device__ __forceinline__ float wred_add_u(float v) {
    v = dpp_add<0xB1>(v);    // quad_perm xor1
    v = dpp_add<0x4E>(v);    // quad_perm xor2
    v = dpp_add<0x141>(v);   // row_half_mirror
    v = dpp_add<0x140>(v);   // row_mirror -> row sums
    v = dpp_add<0x142>(v);   // row_bcast15
    v = dpp_add<0x143>(v);   // row_bcast31 -> lane63 = total
    return __int_as_float(__builtin_amdgcn_readlane(__float_as_int(v), 63));
}
template <int CTRL>
__device__ __forceinline__ float dpp_max(float v) {
    return fmaxf(v, __int_as_float(__builtin_amdgcn_update_dpp(
        0, __float_as_int(v), CTRL, 0xF, 0xF, true)));
}
__device__ __forceinline__ float wred_max(float v) {   // setup-only, verified path
    v = dpp_max<0xB1>(v);
    v = dpp_max<0x4E>(v);
    v = dpp_max<0x141>(v);
    v = dpp_max<0x140>(v);
    v = fmaxf(v, __shfl_xor(v, 16));
    v = fmaxf(v, __shfl_xor(v, 32));
    return v;
}
__device__ __forceinline__ v2f v2max(v2f a, v2f b) { return __builtin_elementwise_max(a, b); }
__device__ __forceinline__ float dot4(const float4& a, const float4& b) {
    return a.x * b.x + a.y * b.y + a.z * b.z + a.w * b.w;
}

// TWO (g,k) problems per wave: (g,k0) and (g,k0+8); x loads/x2/act shared.
// Per-problem math is the verified scheme: log-domain L (row max 0),
// fresh per-node row shift every iteration, exact g-update with +g2, exact
// iteration-1 via per-column shift csh. Iteration state held as v2f pairs
// (v_pk_*_f32 packed VALU) and reductions all-DPP (no ds_swizzle).
// Best-measured configuration of the session (R18: 346 us kernel).
__global__ __launch_bounds__(64) void sinkhorn_tw_k(
    const float* __restrict__ x, const float* __restrict__ tplt,
    const float* __restrict__ q0, const int* __restrict__ starts,
    const int* __restrict__ counts, float* __restrict__ out, int G)
{
    const int bid  = blockIdx.x;
    const int g    = bid % G;      // same-g blocks land on same XCD (G % 8 == 0)
    const int k0   = bid / G;      // k0 in [0,8); problems k0 and k0+8
    const int lane = threadIdx.x;

    const int start = starts[g];
    const int count = counts[g];
    const float a   = 1.0f / (float)count;
    const float la2 = -LOG2F((float)count);            // log2(a)

    // lbla[p][m] = log2_softmax(q0[k,:]) - la2  (stored as v2f pairs)
    v2f lblav[NPROB][M2];
#pragma unroll
    for (int p = 0; p < NPROB; ++p) {
        const float* qk = q0 + (k0 + 8 * p) * M_NODES;
        float qv[M_NODES];
        float qmax = NEG_BIG;
#pragma unroll
        for (int m = 0; m < M_NODES; ++m) { qv[m] = qk[m]; qmax = fmaxf(qmax, qv[m]); }
        float qs = 0.f;
#pragma unroll
        for (int m = 0; m < M_NODES; ++m) {
            qv[m] = (qv[m] - qmax) * LOG2E;
            qs += EXP2F(qv[m]);
        }
        const float corr = LOG2F(qs);
#pragma unroll
        for (int mm = 0; mm < M2; ++mm)
            lblav[p][mm] = (v2f){qv[2 * mm] - corr - la2, qv[2 * mm + 1] - corr - la2};
    }

    bool act[NMAX];
#pragma unroll
    for (int i = 0; i < NMAX; ++i) act[i] = (lane + i * 64) < count;

    // Lv[p][i][mm] = (negC*log2e) - nsh_i, as v2f pairs (log domain, <= 0)
    v2f Lv[NPROB][NMAX][M2];
    float nsum[NPROB];
    v2f cshv[NPROB][M2];
    {
        const float* Tk0 = tplt + (size_t)k0 * M_NODES * DFEAT;
        const float* Tk1 = tplt + (size_t)(k0 + 8) * M_NODES * DFEAT;
        float x2[NMAX];
        v2f t2v[NPROB][M2];
#pragma unroll
        for (int i = 0; i < NMAX; ++i) {
            x2[i] = 0.f;
#pragma unroll
            for (int p = 0; p < NPROB; ++p)
#pragma unroll
                for (int mm = 0; mm < M2; ++mm) Lv[p][i][mm] = (v2f){0.f, 0.f};
        }
#pragma unroll
        for (int p = 0; p < NPROB; ++p)
#pragma unroll
            for (int mm = 0; mm < M2; ++mm) t2v[p][mm] = (v2f){0.f, 0.f};

        for (int j = 0; j < DFEAT; j += 4) {
            float4 xv[NMAX];
#pragma unroll
            for (int i = 0; i < NMAX; ++i) {
                if (act[i]) {
                    xv[i] = *(const float4*)(x + (size_t)(start + lane + i * 64) * DFEAT + j);
                } else {
                    xv[i].x = xv[i].y = xv[i].z = xv[i].w = 0.f;
                }
                x2[i] += dot4(xv[i], xv[i]);
            }
#pragma unroll
            for (int mm = 0; mm < M2; ++mm) {
                const float4 ta0 = *(const float4*)(Tk0 + (2 * mm)     * DFEAT + j);
                const float4 tb0 = *(const float4*)(Tk0 + (2 * mm + 1) * DFEAT + j);
                const float4 ta1 = *(const float4*)(Tk1 + (2 * mm)     * DFEAT + j);
                const float4 tb1 = *(const float4*)(Tk1 + (2 * mm + 1) * DFEAT + j);
                t2v[0][mm] += (v2f){dot4(ta0, ta0), dot4(tb0, tb0)};
                t2v[1][mm] += (v2f){dot4(ta1, ta1), dot4(tb1, tb1)};
#pragma unroll
                for (int i = 0; i < NMAX; ++i) {
                    Lv[0][i][mm] += (v2f){dot4(xv[i], ta0), dot4(xv[i], tb0)};
                    Lv[1][i][mm] += (v2f){dot4(xv[i], ta1), dot4(xv[i], tb1)};
                }
            }
        }
#pragma unroll
        for (int p = 0; p < NPROB; ++p) {
            nsum[p] = 0.f;
#pragma unroll
            for (int i = 0; i < NMAX; ++i) {
                const v2f x2v = {x2[i], x2[i]};
                v2f mxv = (v2f){NEG_BIG, NEG_BIG};
#pragma unroll
                for (int mm = 0; mm < M2; ++mm) {
                    Lv[p][i][mm] = (Lv[p][i][mm] * 2.f - x2v - t2v[p][mm]) * LOG2E; // negC2
                    mxv = v2max(mxv, Lv[p][i][mm]);
                }
                const float mx = fmaxf(mxv.x, mxv.y);
                if (act[i]) nsum[p] += mx;
                const v2f mxb = {mx, mx};
#pragma unroll
                for (int mm = 0; mm < M2; ++mm) Lv[p][i][mm] -= mxb;   // <= 0
            }
            // per-column max over active entries (setup-only, shfl path)
            float csh[M_NODES];
#pragma unroll
            for (int m = 0; m < M_NODES; ++m) {
                float c = NEG_BIG;
#pragma unroll
                for (int i = 0; i < NMAX; ++i) {
                    const float lv = (m & 1) ? Lv[p][i][m >> 1].y : Lv[p][i][m >> 1].x;
                    c = act[i] ? fmaxf(c, lv) : c;
                }
                csh[m] = wred_max(c);
            }
#pragma unroll
            for (int mm = 0; mm < M2; ++mm) cshv[p][mm] = (v2f){csh[2 * mm], csh[2 * mm + 1]};
        }
    }

    v2f g2v[NPROB][M2];

    // ---- iteration 1: g = 0, exact with per-column shift csh ----
#pragma unroll
    for (int p = 0; p < NPROB; ++p) {
        v2f w0v[M2], acc[M2];
#pragma unroll
        for (int mm = 0; mm < M2; ++mm) {
            w0v[mm] = (v2f){EXP2F(cshv[p][mm].x), EXP2F(cshv[p][mm].y)};
            acc[mm] = (v2f){0.f, 0.f};
        }
#pragma unroll
        for (int i = 0; i < NMAX; ++i) {
            if (act[i]) {
                v2f Ev[M2];
                v2f Dp = (v2f){0.f, 0.f};
#pragma unroll
                for (int mm = 0; mm < M2; ++mm) {
                    Ev[mm] = (v2f){EXP2F(Lv[p][i][mm].x - cshv[p][mm].x),
                                   EXP2F(Lv[p][i][mm].y - cshv[p][mm].y)};
                    Dp += Ev[mm] * w0v[mm];              // = sum 2^L per pair
                }
                const float D = Dp.x + Dp.y;             // >= 1
                const float r = __builtin_amdgcn_rcpf(D);
                const v2f rv = {r, r};
#pragma unroll
                for (int mm = 0; mm < M2; ++mm) acc[mm] += Ev[mm] * rv;
            }
        }
#pragma unroll
        for (int mm = 0; mm < M2; ++mm) {
            const float s0 = wred_add_u(acc[mm].x);
            const float s1 = wred_add_u(acc[mm].y);
            g2v[p][mm].x = lblav[p][mm].x - cshv[p][mm].x - LOG2F(fmaxf(s0, 1e-35f));
            g2v[p][mm].y = lblav[p][mm].y - cshv[p][mm].y - LOG2F(fmaxf(s1, 1e-35f));
        }
    }

    // ---- iterations 2..N_ITER: fresh per-node row shift each time ----
    for (int it = 1; it < N_ITER; ++it) {
        v2f acc[NPROB][M2];
#pragma unroll
        for (int p = 0; p < NPROB; ++p)
#pragma unroll
            for (int mm = 0; mm < M2; ++mm) acc[p][mm] = (v2f){0.f, 0.f};

#pragma unroll
        for (int i = 0; i < NMAX; ++i) {
            if (act[i]) {
#pragma unroll
                for (int p = 0; p < NPROB; ++p) {
                    v2f z[M2];
#pragma unroll
                    for (int mm = 0; mm < M2; ++mm) z[mm] = g2v[p][mm] + Lv[p][i][mm];
                    v2f mzv = v2max(z[0], z[1]);
                    mzv = v2max(mzv, z[2]);
                    mzv = v2max(mzv, z[3]);
                    mzv = v2max(mzv, z[4]);
                    const float zmax = fmaxf(mzv.x, mzv.y);
                    const v2f zb = {zmax, zmax};
                    v2f e[M2];
                    v2f Dp = (v2f){0.f, 0.f};
#pragma unroll
                    for (int mm = 0; mm < M2; ++mm) {
                        const v2f d = z[mm] - zb;
                        e[mm] = (v2f){EXP2F(d.x), EXP2F(d.y)};
                        Dp += e[mm];
                    }
                    const float D = Dp.x + Dp.y;         // in [1,10]
                    const float r = __builtin_amdgcn_rcpf(D);
                    const v2f rv = {r, r};
#pragma unroll
                    for (int mm = 0; mm < M2; ++mm) acc[p][mm] += e[mm] * rv;
                }
            }
        }
#pragma unroll
        for (int p = 0; p < NPROB; ++p)
#pragma unroll
            for (int mm = 0; mm < M2; ++mm) {
                const float s0 = wred_add_u(acc[p][mm].x);
                const float s1 = wred_add_u(acc[p][mm].y);
                g2v[p][mm].x = lblav[p][mm].x + g2v[p][mm].x - LOG2F(fmaxf(s0, 1e-35f));
                g2v[p][mm].y = lblav[p][mm].y + g2v[p][mm].y - LOG2F(fmaxf(s1, 1e-35f));
            }
    }

    // ---- epilogue: final f fused with transport cost ----
    // per_node = -a*ln2*( nsh_i + r * sum_m e_m L_m ); nsh pre-summed in nsum
#pragma unroll
    for (int p = 0; p < NPROB; ++p) {
        float accum = nsum[p];
#pragma unroll
        for (int i = 0; i < NMAX; ++i) {
            if (act[i]) {
                v2f z[M2];
#pragma unroll
                for (int mm = 0; mm < M2; ++mm) z[mm] = g2v[p][mm] + Lv[p][i][mm];
                v2f mzv = v2max(z[0], z[1]);
                mzv = v2max(mzv, z[2]);
                mzv = v2max(mzv, z[3]);
                mzv = v2max(mzv, z[4]);
                const float zmax = fmaxf(mzv.x, mzv.y);
                const v2f zb = {zmax, zmax};
                v2f e[M2];
                v2f Dp = (v2f){0.f, 0.f};
                v2f qv = (v2f){0.f, 0.f};
#pragma unroll
                for (int mm = 0; mm < M2; ++mm) {
                    const v2f d = z[mm] - zb;
                    e[mm] = (v2f){EXP2F(d.x), EXP2F(d.y)};
                    Dp += e[mm];
                    qv += e[mm] * Lv[p][i][mm];
                }
                const float D = Dp.x + Dp.y;
                const float r = __builtin_amdgcn_rcpf(D);
                accum += (qv.x + qv.y) * r;
            }
        }
        accum = wred_add_u(accum);
        if (lane == 0) out[(size_t)g * K_TPLT + (k0 + 8 * p)] = -a * LN2 * accum;
    }
}

extern "C" void kernel_launch(void* const* d_in, const int* in_sizes, int n_in,
                              void* d_out, int out_size, void* d_ws, size_t ws_size,
                              hipStream_t stream) {
    const float* x    = (const float*)d_in[0];
    const float* tplt = (const float*)d_in[1];
    const float* q0   = (const float*)d_in[2];
    const int* batch  = (const int*)d_in[3];
    const int N = in_sizes[3];
    const int G = out_size / K_TPLT;

    int* counts = (int*)d_ws;
    int* starts = counts + G;

    zero_counts_k<<<(G + 255) / 256, 256, 0, stream>>>(counts, G);
    count_nodes_k<<<(N + 255) / 256, 256, 0, stream>>>(batch, counts, N);
    scan_counts_k<<<1, 256, 0, stream>>>(counts, starts, G);
    sinkhorn_tw_k<<<G * (K_TPLT / 2), 64, 0, stream>>>(x, tplt, q0, starts, counts,
                                                       (float*)d_out, G);
}